// Round 1
// baseline (186.944 us; speedup 1.0000x reference)
//
#include <hip/hip_runtime.h>
#include <math.h>

#define B_  16
#define C_  256
#define T_  4096
#define DT_ 512
#define NH_ 8
#define HD_ 32

// ---------------------------------------------------------------------------
// K1: per-batch small GEMMs: text projection -> q -> kq/qkb, gate g
// ---------------------------------------------------------------------------
__global__ void k1_prep(const float* __restrict__ F_text,
                        const float* __restrict__ F_unified,
                        const float* __restrict__ F_teacher,
                        const float* __restrict__ tp_w1, const float* __restrict__ tp_b1,
                        const float* __restrict__ tp_w2, const float* __restrict__ tp_b2,
                        const float* __restrict__ q_w,  const float* __restrict__ q_b,
                        const float* __restrict__ k_w,  const float* __restrict__ k_b,
                        const float* __restrict__ fa_w, const float* __restrict__ fa_b,
                        const float* __restrict__ gp_w, const float* __restrict__ gp_b,
                        float* __restrict__ kq, float* __restrict__ qkb,
                        float* __restrict__ gout)
{
    int b = blockIdx.x, tid = threadIdx.x;
    __shared__ float ft[DT_];
    __shared__ float t1[C_];
    __shared__ float tv[C_];
    __shared__ float qs[C_];
    __shared__ float red[8];

    ft[tid]       = F_text[b*DT_ + tid];
    ft[tid + 256] = F_text[b*DT_ + 256 + tid];
    __syncthreads();

    // t1 = gelu(ft @ tp_w1 + b1)   (exact gelu, erf-based)
    float a = tp_b1[tid];
    #pragma unroll 8
    for (int i = 0; i < DT_; i++) a += ft[i] * tp_w1[i*C_ + tid];
    a = 0.5f * a * (1.0f + erff(a * 0.70710678118654752f));
    t1[tid] = a;
    __syncthreads();

    // tv = t1 @ tp_w2 + b2
    float a2 = tp_b2[tid];
    #pragma unroll 8
    for (int i = 0; i < C_; i++) a2 += t1[i] * tp_w2[i*C_ + tid];
    tv[tid] = a2;
    __syncthreads();

    // q = tv @ q_w + q_b
    float qv = q_b[tid];
    #pragma unroll 8
    for (int i = 0; i < C_; i++) qv += tv[i] * q_w[i*C_ + tid];
    qs[tid] = qv;
    __syncthreads();

    // kq[b,h,c] = sum_d k_w[c, h*32+d] * q[h*32+d]   (thread = c)
    #pragma unroll
    for (int h = 0; h < NH_; h++) {
        float s = 0.f;
        #pragma unroll 8
        for (int d = 0; d < HD_; d++) s += k_w[tid*C_ + h*HD_ + d] * qs[h*HD_ + d];
        kq[(b*NH_ + h)*C_ + tid] = s;
    }
    if (tid < NH_) {
        float s = 0.f;
        #pragma unroll 8
        for (int d = 0; d < HD_; d++) s += qs[tid*HD_ + d] * k_b[tid*HD_ + d];
        qkb[b*NH_ + tid] = s;
    }

    // gate: a = softmax over {unified, teacher} of (f . fa_w + fa_b)
    float p0 = F_unified[b*DT_ + tid]*fa_w[tid] + F_unified[b*DT_ + 256 + tid]*fa_w[256 + tid];
    float p1 = F_teacher[b*DT_ + tid]*fa_w[tid] + F_teacher[b*DT_ + 256 + tid]*fa_w[256 + tid];
    #pragma unroll
    for (int o = 32; o; o >>= 1) { p0 += __shfl_xor(p0, o); p1 += __shfl_xor(p1, o); }
    int wid = tid >> 6, lane = tid & 63;
    if (lane == 0) { red[wid] = p0; red[4 + wid] = p1; }
    __syncthreads();
    float s0 = red[0] + red[1] + red[2] + red[3] + fa_b[0];
    float s1 = red[4] + red[5] + red[6] + red[7] + fa_b[0];
    float mm = fmaxf(s0, s1);
    float e0 = expf(s0 - mm), e1 = expf(s1 - mm);
    float inv = 1.0f / (e0 + e1);
    float a0 = e0 * inv, a1 = e1 * inv;

    __syncthreads();  // done with ft in its old role
    ft[tid]       = a0*F_unified[b*DT_ + tid]       + a1*F_teacher[b*DT_ + tid];
    ft[tid + 256] = a0*F_unified[b*DT_ + 256 + tid] + a1*F_teacher[b*DT_ + 256 + tid];
    __syncthreads();

    float gv = gp_b[tid];
    #pragma unroll 8
    for (int i = 0; i < DT_; i++) gv += ft[i] * gp_w[i*C_ + tid];
    gout[b*C_ + tid] = 1.0f / (1.0f + expf(-gv));
}

// ---------------------------------------------------------------------------
// K2: score partials.  scores_p[chalf][b][h][t] = sum_{c in half} Fvis[b,c,t]*kq[b,h,c]
// ---------------------------------------------------------------------------
__global__ void k2_scores(const float* __restrict__ F_vis,
                          const float* __restrict__ kq,
                          float* __restrict__ sp)
{
    int chunk = blockIdx.x;          // 0..31
    int b     = blockIdx.y;
    int chalf = chunk >> 4;          // 0..1
    int tch   = chunk & 15;          // 0..15
    int tid   = threadIdx.x;
    int t     = tch*256 + tid;

    __shared__ __align__(16) float kqT[128][8];
    for (int idx = tid; idx < 1024; idx += 256) {
        int h = idx >> 7, cl = idx & 127;
        kqT[cl][h] = kq[(b*NH_ + h)*C_ + chalf*128 + cl];
    }
    __syncthreads();

    const float4* kqT4 = reinterpret_cast<const float4*>(&kqT[0][0]);
    const float* fv = F_vis + ((size_t)b*C_ + chalf*128) * T_ + t;

    float acc[8] = {0,0,0,0,0,0,0,0};
    #pragma unroll 4
    for (int cl = 0; cl < 128; cl++) {
        float v  = fv[(size_t)cl * T_];
        float4 ka = kqT4[cl*2], kb4 = kqT4[cl*2 + 1];
        acc[0] += v*ka.x;  acc[1] += v*ka.y;  acc[2] += v*ka.z;  acc[3] += v*ka.w;
        acc[4] += v*kb4.x; acc[5] += v*kb4.y; acc[6] += v*kb4.z; acc[7] += v*kb4.w;
    }
    #pragma unroll
    for (int h = 0; h < NH_; h++)
        sp[(((size_t)chalf*B_ + b)*NH_ + h)*T_ + t] = acc[h];
}

// ---------------------------------------------------------------------------
// K3: softmax over T per (b,h); writes attn output (output #1)
// ---------------------------------------------------------------------------
__global__ void k3_softmax(const float* __restrict__ sp,
                           const float* __restrict__ qkb,
                           float* __restrict__ attn)
{
    int h = blockIdx.x, b = blockIdx.y, tid = threadIdx.x;
    const float scale = 0.176776695296636893f;  // 32^-0.5
    float bias = qkb[b*NH_ + h];
    const float* p0 = sp + (((size_t)0*B_ + b)*NH_ + h)*T_;
    const float* p1 = sp + (((size_t)1*B_ + b)*NH_ + h)*T_;

    float s[16];
    float m = -1e30f;
    #pragma unroll
    for (int k = 0; k < 16; k++) {
        int t = tid + k*256;
        float v = (p0[t] + p1[t] + bias) * scale;
        s[k] = v; m = fmaxf(m, v);
    }
    __shared__ float red[8];
    #pragma unroll
    for (int o = 32; o; o >>= 1) m = fmaxf(m, __shfl_xor(m, o));
    int wid = tid >> 6, lane = tid & 63;
    if (lane == 0) red[wid] = m;
    __syncthreads();
    m = fmaxf(fmaxf(red[0], red[1]), fmaxf(red[2], red[3]));

    float sum = 0.f;
    #pragma unroll
    for (int k = 0; k < 16; k++) { s[k] = expf(s[k] - m); sum += s[k]; }
    #pragma unroll
    for (int o = 32; o; o >>= 1) sum += __shfl_xor(sum, o);
    if (lane == 0) red[4 + wid] = sum;
    __syncthreads();
    sum = red[4] + red[5] + red[6] + red[7];
    float inv = 1.0f / sum;

    float* ap = attn + ((size_t)b*NH_ + h)*T_;
    #pragma unroll
    for (int k = 0; k < 16; k++) ap[tid + k*256] = s[k] * inv;
}

// ---------------------------------------------------------------------------
// K4: xa[b,h,c] = sum_t attn[b,h,t] * F_vis[b,c,t]   (wave owns 4 channels)
// ---------------------------------------------------------------------------
__global__ void k4_xa(const float* __restrict__ F_vis,
                      const float* __restrict__ attn,
                      float* __restrict__ xa)
{
    int b = blockIdx.y;
    int tid = threadIdx.x, wid = tid >> 6, lane = tid & 63;
    int c0 = blockIdx.x*16 + wid*4;

    const float* ab = attn + (size_t)b*NH_*T_;
    const float* fb = F_vis + (size_t)b*C_*T_;

    float acc[4][8];
    #pragma unroll
    for (int j = 0; j < 4; j++)
        #pragma unroll
        for (int h = 0; h < 8; h++) acc[j][h] = 0.f;

    #pragma unroll 2
    for (int it = 0; it < 64; it++) {
        int t = it*64 + lane;
        float av[8];
        #pragma unroll
        for (int h = 0; h < 8; h++) av[h] = ab[(size_t)h*T_ + t];
        #pragma unroll
        for (int j = 0; j < 4; j++) {
            float v = fb[(size_t)(c0 + j)*T_ + t];
            #pragma unroll
            for (int h = 0; h < 8; h++) acc[j][h] += v * av[h];
        }
    }
    #pragma unroll
    for (int j = 0; j < 4; j++)
        #pragma unroll
        for (int h = 0; h < 8; h++) {
            float v = acc[j][h];
            #pragma unroll
            for (int o = 32; o; o >>= 1) v += __shfl_xor(v, o);
            if (lane == 0) xa[((size_t)b*NH_ + h)*C_ + c0 + j] = v;
        }
}

// ---------------------------------------------------------------------------
// K5: z = (xa @ v_w + v_b) @ o_w + o_b;  gz = g * z
// ---------------------------------------------------------------------------
__global__ void k5_z(const float* __restrict__ xa,
                     const float* __restrict__ v_w, const float* __restrict__ v_b,
                     const float* __restrict__ o_w, const float* __restrict__ o_b,
                     const float* __restrict__ g,   float* __restrict__ gz)
{
    int b = blockIdx.x, j = threadIdx.x;
    __shared__ float zp[C_];
    int h = j >> 5;
    float s = v_b[j];
    const float* xr = xa + ((size_t)b*NH_ + h)*C_;
    #pragma unroll 8
    for (int c = 0; c < C_; c++) s += xr[c] * v_w[c*C_ + j];
    zp[j] = s;
    __syncthreads();
    float z = o_b[j];
    #pragma unroll 8
    for (int i = 0; i < C_; i++) z += zp[i] * o_w[i*C_ + j];
    gz[b*C_ + j] = g[b*C_ + j] * z;
}

// ---------------------------------------------------------------------------
// K6: y = F_vis + gz (broadcast over t); LayerNorm over c; out[b,c,t]
// ---------------------------------------------------------------------------
__global__ void k6_ln(const float* __restrict__ F_vis,
                      const float* __restrict__ gz,
                      const float* __restrict__ ln_g, const float* __restrict__ ln_b,
                      float* __restrict__ out)
{
    int b = blockIdx.y;
    int t = blockIdx.x*256 + threadIdx.x;
    const float* fv  = F_vis + (size_t)b*C_*T_ + t;
    const float* gzb = gz + b*C_;

    float sum = 0.f, sq = 0.f;
    #pragma unroll 8
    for (int c = 0; c < C_; c++) {
        float x = fv[(size_t)c*T_] + gzb[c];
        sum += x; sq += x*x;
    }
    float mu   = sum * (1.0f/C_);
    float var  = sq * (1.0f/C_) - mu*mu;
    float rstd = rsqrtf(fmaxf(var, 0.f) + 1e-5f);

    float* op = out + (size_t)b*C_*T_ + t;
    #pragma unroll 8
    for (int c = 0; c < C_; c++) {
        float x = fv[(size_t)c*T_] + gzb[c];
        op[(size_t)c*T_] = (x - mu)*rstd*ln_g[c] + ln_b[c];
    }
}

// ---------------------------------------------------------------------------
extern "C" void kernel_launch(void* const* d_in, const int* in_sizes, int n_in,
                              void* d_out, int out_size, void* d_ws, size_t ws_size,
                              hipStream_t stream)
{
    const float* F_vis     = (const float*)d_in[0];
    const float* F_text    = (const float*)d_in[1];
    const float* F_unified = (const float*)d_in[2];
    const float* F_teacher = (const float*)d_in[3];
    const float* tp_w1 = (const float*)d_in[4];
    const float* tp_b1 = (const float*)d_in[5];
    const float* tp_w2 = (const float*)d_in[6];
    const float* tp_b2 = (const float*)d_in[7];
    const float* q_w   = (const float*)d_in[8];
    const float* q_b   = (const float*)d_in[9];
    const float* k_w   = (const float*)d_in[10];
    const float* k_b   = (const float*)d_in[11];
    const float* v_w   = (const float*)d_in[12];
    const float* v_b   = (const float*)d_in[13];
    const float* o_w   = (const float*)d_in[14];
    const float* o_b   = (const float*)d_in[15];
    const float* fa_w  = (const float*)d_in[16];
    const float* fa_b  = (const float*)d_in[17];
    const float* gp_w  = (const float*)d_in[18];
    const float* gp_b  = (const float*)d_in[19];
    const float* ln_g  = (const float*)d_in[20];
    const float* ln_b  = (const float*)d_in[21];

    float* ws  = (float*)d_ws;
    float* kq  = ws;                    // 16*8*256          = 32768
    float* qkb = ws + 32768;            // 128
    float* g   = ws + 32896;            // 4096
    float* gz  = ws + 36992;            // 4096
    float* xa  = ws + 41088;            // 32768  (total 73856 floats = 295KB)

    float* out  = (float*)d_out;
    float* attn = out + (size_t)B_*C_*T_;        // output #1 region
    float* sp   = out;                           // scratch in out-region (overwritten by K6)

    k1_prep<<<B_, 256, 0, stream>>>(F_text, F_unified, F_teacher,
                                    tp_w1, tp_b1, tp_w2, tp_b2,
                                    q_w, q_b, k_w, k_b,
                                    fa_w, fa_b, gp_w, gp_b,
                                    kq, qkb, g);
    k2_scores<<<dim3(32, B_), 256, 0, stream>>>(F_vis, kq, sp);
    k3_softmax<<<dim3(NH_, B_), 256, 0, stream>>>(sp, qkb, attn);
    k4_xa<<<dim3(16, B_), 256, 0, stream>>>(F_vis, attn, xa);
    k5_z<<<B_, 256, 0, stream>>>(xa, v_w, v_b, o_w, o_b, g, gz);
    k6_ln<<<dim3(16, B_), 256, 0, stream>>>(F_vis, gz, ln_g, ln_b, out);
}

// Round 2
// 165.307 us; speedup vs baseline: 1.1309x; 1.1309x over previous
//
#include <hip/hip_runtime.h>
#include <math.h>

#define B_  16
#define C_  256
#define T_  4096
#define DT_ 512
#define NH_ 8
#define HD_ 32

// ---------------------------------------------------------------------------
// K1: per-batch small GEMM chain, 1024 threads, 4-way split-K per phase.
//     t1 = gelu(F_text@W1+b1); tv = t1@W2+b2; q = tv@q_w+q_b;
//     kq[h,c] = sum_d k_w[c,hd+d] q[hd+d]; qkb[h] = q_h . k_b_h;
//     gate: a = softmax over {U,T}; g = sigmoid(f_cond@gp_w+gp_b)
// ---------------------------------------------------------------------------
__global__ __launch_bounds__(1024) void k1_prep(
                        const float* __restrict__ F_text,
                        const float* __restrict__ F_unified,
                        const float* __restrict__ F_teacher,
                        const float* __restrict__ tp_w1, const float* __restrict__ tp_b1,
                        const float* __restrict__ tp_w2, const float* __restrict__ tp_b2,
                        const float* __restrict__ q_w,  const float* __restrict__ q_b,
                        const float* __restrict__ k_w,  const float* __restrict__ k_b,
                        const float* __restrict__ fa_w, const float* __restrict__ fa_b,
                        const float* __restrict__ gp_w, const float* __restrict__ gp_b,
                        float* __restrict__ kq, float* __restrict__ qkb,
                        float* __restrict__ gout)
{
    int b   = blockIdx.x;
    int tid = threadIdx.x;
    int c   = tid & 255;
    int ks  = tid >> 8;              // 0..3 K-slice

    __shared__ float part[4][256];
    __shared__ float stage[256];     // holds t1, then tv, then q
    __shared__ float red[16];

    // ---- phase 1: t1 = gelu(F_text @ tp_w1 + b1), K=512 split 4x128
    const float* ftb = F_text + b*DT_;
    {
        float acc = 0.f;
        #pragma unroll 8
        for (int i = ks*128; i < ks*128 + 128; ++i)
            acc += ftb[i] * tp_w1[i*C_ + c];
        part[ks][c] = acc;
    }
    __syncthreads();
    if (tid < 256) {
        float a = part[0][tid] + part[1][tid] + part[2][tid] + part[3][tid] + tp_b1[tid];
        a = 0.5f * a * (1.0f + erff(a * 0.70710678118654752f));
        stage[tid] = a;
    }
    __syncthreads();

    // ---- phase 2: tv = t1 @ tp_w2 + b2, K=256 split 4x64
    {
        float acc = 0.f;
        #pragma unroll 8
        for (int i = ks*64; i < ks*64 + 64; ++i)
            acc += stage[i] * tp_w2[i*C_ + c];
        part[ks][c] = acc;
    }
    __syncthreads();
    if (tid < 256)
        stage[tid] = part[0][tid] + part[1][tid] + part[2][tid] + part[3][tid] + tp_b2[tid];
    __syncthreads();
    // NOTE: stage now holds tv but phase-3 must read tv; re-sync pattern:
    // the write above races with phase-3 reads without a barrier -> barrier done.

    // ---- phase 3: q = tv @ q_w + q_b, K=256 split 4x64
    {
        float acc = 0.f;
        #pragma unroll 8
        for (int i = ks*64; i < ks*64 + 64; ++i)
            acc += stage[i] * q_w[i*C_ + c];
        part[ks][c] = acc;
    }
    __syncthreads();
    if (tid < 256)
        stage[tid] = part[0][tid] + part[1][tid] + part[2][tid] + part[3][tid] + q_b[tid];
    __syncthreads();
    // stage = q[256]

    // ---- phase 4: kq[h,c] (2 heads per K-slice), qkb[h]
    #pragma unroll
    for (int hh = ks*2; hh < ks*2 + 2; ++hh) {
        const float4* kr = reinterpret_cast<const float4*>(k_w + (size_t)c*C_ + hh*HD_);
        float s = 0.f;
        #pragma unroll
        for (int j = 0; j < 8; ++j) {
            float4 kv = kr[j];
            s += kv.x*stage[hh*HD_ + j*4 + 0] + kv.y*stage[hh*HD_ + j*4 + 1]
               + kv.z*stage[hh*HD_ + j*4 + 2] + kv.w*stage[hh*HD_ + j*4 + 3];
        }
        kq[(b*NH_ + hh)*C_ + c] = s;
    }
    if (tid < 256) {
        float p = stage[tid] * k_b[tid];
        #pragma unroll
        for (int o = 16; o; o >>= 1) p += __shfl_xor(p, o);
        if ((tid & 31) == 0) qkb[b*NH_ + (tid >> 5)] = p;
    }

    // ---- phase 5: gate
    const float* U  = F_unified + b*DT_;
    const float* Tt = F_teacher + b*DT_;
    {
        float x;
        if (tid < 512) x = U[tid] * fa_w[tid];
        else           x = Tt[tid - 512] * fa_w[tid - 512];
        #pragma unroll
        for (int o = 32; o; o >>= 1) x += __shfl_xor(x, o);
        if ((tid & 63) == 0) red[tid >> 6] = x;
    }
    __syncthreads();
    float s0 = fa_b[0], s1 = fa_b[0];
    #pragma unroll
    for (int wv = 0; wv < 8; ++wv) { s0 += red[wv]; s1 += red[8 + wv]; }
    float mm = fmaxf(s0, s1);
    float e0 = expf(s0 - mm), e1 = expf(s1 - mm);
    float inv = 1.0f / (e0 + e1);
    float a0 = e0 * inv, a1 = e1 * inv;

    {
        float ag = 0.f;
        #pragma unroll 4
        for (int i = ks*128; i < ks*128 + 128; ++i) {
            float fc = a0 * U[i] + a1 * Tt[i];
            ag += fc * gp_w[i*C_ + c];
        }
        part[ks][c] = ag;
    }
    __syncthreads();
    if (tid < 256) {
        float gv = part[0][tid] + part[1][tid] + part[2][tid] + part[3][tid] + gp_b[tid];
        gout[b*C_ + tid] = 1.0f / (1.0f + expf(-gv));
    }
}

// ---------------------------------------------------------------------------
// K2: score partials.  scores_p[chalf][b][h][t] = sum_{c in half} Fvis[b,c,t]*kq[b,h,c]
// ---------------------------------------------------------------------------
__global__ void k2_scores(const float* __restrict__ F_vis,
                          const float* __restrict__ kq,
                          float* __restrict__ sp)
{
    int chunk = blockIdx.x;          // 0..31
    int b     = blockIdx.y;
    int chalf = chunk >> 4;          // 0..1
    int tch   = chunk & 15;          // 0..15
    int tid   = threadIdx.x;
    int t     = tch*256 + tid;

    __shared__ __align__(16) float kqT[128][8];
    for (int idx = tid; idx < 1024; idx += 256) {
        int h = idx >> 7, cl = idx & 127;
        kqT[cl][h] = kq[(b*NH_ + h)*C_ + chalf*128 + cl];
    }
    __syncthreads();

    const float4* kqT4 = reinterpret_cast<const float4*>(&kqT[0][0]);
    const float* fv = F_vis + ((size_t)b*C_ + chalf*128) * T_ + t;

    float acc[8] = {0,0,0,0,0,0,0,0};
    #pragma unroll 4
    for (int cl = 0; cl < 128; cl++) {
        float v  = fv[(size_t)cl * T_];
        float4 ka = kqT4[cl*2], kb4 = kqT4[cl*2 + 1];
        acc[0] += v*ka.x;  acc[1] += v*ka.y;  acc[2] += v*ka.z;  acc[3] += v*ka.w;
        acc[4] += v*kb4.x; acc[5] += v*kb4.y; acc[6] += v*kb4.z; acc[7] += v*kb4.w;
    }
    #pragma unroll
    for (int h = 0; h < NH_; h++)
        sp[(((size_t)chalf*B_ + b)*NH_ + h)*T_ + t] = acc[h];
}

// ---------------------------------------------------------------------------
// K3: softmax over T per (b,h); writes attn output (output #1)
// ---------------------------------------------------------------------------
__global__ void k3_softmax(const float* __restrict__ sp,
                           const float* __restrict__ qkb,
                           float* __restrict__ attn)
{
    int h = blockIdx.x, b = blockIdx.y, tid = threadIdx.x;
    const float scale = 0.176776695296636893f;  // 32^-0.5
    float bias = qkb[b*NH_ + h];
    const float* p0 = sp + (((size_t)0*B_ + b)*NH_ + h)*T_;
    const float* p1 = sp + (((size_t)1*B_ + b)*NH_ + h)*T_;

    float s[16];
    float m = -1e30f;
    #pragma unroll
    for (int k = 0; k < 16; k++) {
        int t = tid + k*256;
        float v = (p0[t] + p1[t] + bias) * scale;
        s[k] = v; m = fmaxf(m, v);
    }
    __shared__ float red[8];
    #pragma unroll
    for (int o = 32; o; o >>= 1) m = fmaxf(m, __shfl_xor(m, o));
    int wid = tid >> 6, lane = tid & 63;
    if (lane == 0) red[wid] = m;
    __syncthreads();
    m = fmaxf(fmaxf(red[0], red[1]), fmaxf(red[2], red[3]));

    float sum = 0.f;
    #pragma unroll
    for (int k = 0; k < 16; k++) { s[k] = expf(s[k] - m); sum += s[k]; }
    #pragma unroll
    for (int o = 32; o; o >>= 1) sum += __shfl_xor(sum, o);
    if (lane == 0) red[4 + wid] = sum;
    __syncthreads();
    sum = red[4] + red[5] + red[6] + red[7];
    float inv = 1.0f / sum;

    float* ap = attn + ((size_t)b*NH_ + h)*T_;
    #pragma unroll
    for (int k = 0; k < 16; k++) ap[tid + k*256] = s[k] * inv;
}

// ---------------------------------------------------------------------------
// K4: xa[b,h,c] = sum_t attn[b,h,t] * F_vis[b,c,t]   (wave owns 4 channels)
// ---------------------------------------------------------------------------
__global__ void k4_xa(const float* __restrict__ F_vis,
                      const float* __restrict__ attn,
                      float* __restrict__ xa)
{
    int b = blockIdx.y;
    int tid = threadIdx.x, wid = tid >> 6, lane = tid & 63;
    int c0 = blockIdx.x*16 + wid*4;

    const float* ab = attn + (size_t)b*NH_*T_;
    const float* fb = F_vis + (size_t)b*C_*T_;

    float acc[4][8];
    #pragma unroll
    for (int j = 0; j < 4; j++)
        #pragma unroll
        for (int h = 0; h < 8; h++) acc[j][h] = 0.f;

    #pragma unroll 2
    for (int it = 0; it < 64; it++) {
        int t = it*64 + lane;
        float av[8];
        #pragma unroll
        for (int h = 0; h < 8; h++) av[h] = ab[(size_t)h*T_ + t];
        #pragma unroll
        for (int j = 0; j < 4; j++) {
            float v = fb[(size_t)(c0 + j)*T_ + t];
            #pragma unroll
            for (int h = 0; h < 8; h++) acc[j][h] += v * av[h];
        }
    }
    #pragma unroll
    for (int j = 0; j < 4; j++)
        #pragma unroll
        for (int h = 0; h < 8; h++) {
            float v = acc[j][h];
            #pragma unroll
            for (int o = 32; o; o >>= 1) v += __shfl_xor(v, o);
            if (lane == 0) xa[((size_t)b*NH_ + h)*C_ + c0 + j] = v;
        }
}

// ---------------------------------------------------------------------------
// K5: z = (xa @ v_w + v_b) @ o_w + o_b;  gz = g * z
// ---------------------------------------------------------------------------
__global__ void k5_z(const float* __restrict__ xa,
                     const float* __restrict__ v_w, const float* __restrict__ v_b,
                     const float* __restrict__ o_w, const float* __restrict__ o_b,
                     const float* __restrict__ g,   float* __restrict__ gz)
{
    int b = blockIdx.x, j = threadIdx.x;
    __shared__ float zp[C_];
    int h = j >> 5;
    float s = v_b[j];
    const float* xr = xa + ((size_t)b*NH_ + h)*C_;
    #pragma unroll 8
    for (int c = 0; c < C_; c++) s += xr[c] * v_w[c*C_ + j];
    zp[j] = s;
    __syncthreads();
    float z = o_b[j];
    #pragma unroll 8
    for (int i = 0; i < C_; i++) z += zp[i] * o_w[i*C_ + j];
    gz[b*C_ + j] = g[b*C_ + j] * z;
}

// ---------------------------------------------------------------------------
// K6: y = F_vis + gz (broadcast over t); LayerNorm over c; out[b,c,t]
// ---------------------------------------------------------------------------
__global__ void k6_ln(const float* __restrict__ F_vis,
                      const float* __restrict__ gz,
                      const float* __restrict__ ln_g, const float* __restrict__ ln_b,
                      float* __restrict__ out)
{
    int b = blockIdx.y;
    int t = blockIdx.x*256 + threadIdx.x;
    const float* fv  = F_vis + (size_t)b*C_*T_ + t;
    const float* gzb = gz + b*C_;

    float sum = 0.f, sq = 0.f;
    #pragma unroll 8
    for (int c = 0; c < C_; c++) {
        float x = fv[(size_t)c*T_] + gzb[c];
        sum += x; sq += x*x;
    }
    float mu   = sum * (1.0f/C_);
    float var  = sq * (1.0f/C_) - mu*mu;
    float rstd = rsqrtf(fmaxf(var, 0.f) + 1e-5f);

    float* op = out + (size_t)b*C_*T_ + t;
    #pragma unroll 8
    for (int c = 0; c < C_; c++) {
        float x = fv[(size_t)c*T_] + gzb[c];
        op[(size_t)c*T_] = (x - mu)*rstd*ln_g[c] + ln_b[c];
    }
}

// ---------------------------------------------------------------------------
extern "C" void kernel_launch(void* const* d_in, const int* in_sizes, int n_in,
                              void* d_out, int out_size, void* d_ws, size_t ws_size,
                              hipStream_t stream)
{
    const float* F_vis     = (const float*)d_in[0];
    const float* F_text    = (const float*)d_in[1];
    const float* F_unified = (const float*)d_in[2];
    const float* F_teacher = (const float*)d_in[3];
    const float* tp_w1 = (const float*)d_in[4];
    const float* tp_b1 = (const float*)d_in[5];
    const float* tp_w2 = (const float*)d_in[6];
    const float* tp_b2 = (const float*)d_in[7];
    const float* q_w   = (const float*)d_in[8];
    const float* q_b   = (const float*)d_in[9];
    const float* k_w   = (const float*)d_in[10];
    const float* k_b   = (const float*)d_in[11];
    const float* v_w   = (const float*)d_in[12];
    const float* v_b   = (const float*)d_in[13];
    const float* o_w   = (const float*)d_in[14];
    const float* o_b   = (const float*)d_in[15];
    const float* fa_w  = (const float*)d_in[16];
    const float* fa_b  = (const float*)d_in[17];
    const float* gp_w  = (const float*)d_in[18];
    const float* gp_b  = (const float*)d_in[19];
    const float* ln_g  = (const float*)d_in[20];
    const float* ln_b  = (const float*)d_in[21];

    float* ws  = (float*)d_ws;
    float* kq  = ws;                    // 16*8*256          = 32768
    float* qkb = ws + 32768;            // 128
    float* g   = ws + 32896;            // 4096
    float* gz  = ws + 36992;            // 4096
    float* xa  = ws + 41088;            // 32768

    float* out  = (float*)d_out;
    float* attn = out + (size_t)B_*C_*T_;        // output #1 region
    float* sp   = out;                           // scratch in out-region (overwritten by K6)

    k1_prep<<<B_, 1024, 0, stream>>>(F_text, F_unified, F_teacher,
                                     tp_w1, tp_b1, tp_w2, tp_b2,
                                     q_w, q_b, k_w, k_b,
                                     fa_w, fa_b, gp_w, gp_b,
                                     kq, qkb, g);
    k2_scores<<<dim3(32, B_), 256, 0, stream>>>(F_vis, kq, sp);
    k3_softmax<<<dim3(NH_, B_), 256, 0, stream>>>(sp, qkb, attn);
    k4_xa<<<dim3(16, B_), 256, 0, stream>>>(F_vis, attn, xa);
    k5_z<<<B_, 256, 0, stream>>>(xa, v_w, v_b, o_w, o_b, g, gz);
    k6_ln<<<dim3(16, B_), 256, 0, stream>>>(F_vis, gz, ln_g, ln_b, out);
}

// Round 3
// 146.128 us; speedup vs baseline: 1.2793x; 1.1312x over previous
//
#include <hip/hip_runtime.h>
#include <math.h>

#define B_  16
#define C_  256
#define T_  4096
#define DT_ 512
#define NH_ 8
#define HD_ 32

// ---------------------------------------------------------------------------
// gemm16<K,ACT>: out[16][256] = act(x[16][K] @ W[K][256] + bias)
// grid = 16 blocks (16 output cols each), 512 threads = 16 cols x 32 K-slices.
// All 16 batch rows ride in registers: 1 weight load feeds 16 FMAs.
// ACT: 0 = none, 1 = exact gelu
// ---------------------------------------------------------------------------
template<int K, int ACT>
__global__ __launch_bounds__(512) void gemm16(const float* __restrict__ x,
                                              const float* __restrict__ W,
                                              const float* __restrict__ bias,
                                              float* __restrict__ out)
{
    __shared__ float xs[16 * K];
    __shared__ float part[32 * 256];
    int tid = threadIdx.x;
    int c0  = blockIdx.x * 16;

    for (int idx = tid; idx < 16 * K; idx += 512) xs[idx] = x[idx];
    __syncthreads();

    int cl = tid & 15;          // col within chunk
    int ks = tid >> 4;          // 0..31 K-slice
    const int Kc = K / 32;
    int c = c0 + cl;

    float acc[16];
    #pragma unroll
    for (int b = 0; b < 16; ++b) acc[b] = 0.f;

    const float* wp = W + (size_t)(ks * Kc) * 256 + c;
    #pragma unroll
    for (int i = 0; i < Kc; ++i) {
        float w  = wp[(size_t)i * 256];
        int   xi = ks * Kc + i;
        #pragma unroll
        for (int b = 0; b < 16; ++b) acc[b] += xs[b * K + xi] * w;
    }
    #pragma unroll
    for (int b = 0; b < 16; ++b) part[ks * 256 + b * 16 + cl] = acc[b];
    __syncthreads();

    if (tid < 256) {
        int b = tid >> 4, cc = tid & 15;
        float s = 0.f;
        #pragma unroll
        for (int k2 = 0; k2 < 32; ++k2) s += part[k2 * 256 + b * 16 + cc];
        s += bias[c0 + cc];
        if (ACT == 1) s = 0.5f * s * (1.0f + erff(s * 0.70710678118654752f));
        out[b * 256 + c0 + cc] = s;
    }
}

// ---------------------------------------------------------------------------
// k_kq: kq[b,h,c] = sum_d k_w[c, h*32+d] * q[b, h*32+d];  qkb[b,h] = q_h . k_b_h
// grid 16 (c-chunks of 16), 256 threads = 16 cl x 8 h x 2 b-halves.
// d-loop rotated by h*4 so the 8 h-groups in a wave hit 8 distinct LDS banks.
// ---------------------------------------------------------------------------
__global__ __launch_bounds__(256) void k_kq(const float* __restrict__ q,
                                            const float* __restrict__ k_w,
                                            const float* __restrict__ k_b,
                                            float* __restrict__ kq,
                                            float* __restrict__ qkb)
{
    __shared__ float qs[4096];
    int tid = threadIdx.x;
    #pragma unroll
    for (int idx = tid; idx < 4096; idx += 256) qs[idx] = q[idx];
    __syncthreads();

    int cl = tid >> 4;          // 0..15
    int h  = (tid >> 1) & 7;    // 0..7
    int bh = tid & 1;           // 0..1
    int c  = blockIdx.x * 16 + cl;

    const float* kwp = k_w + (size_t)c * 256 + h * 32;
    float acc[8] = {0,0,0,0,0,0,0,0};
    #pragma unroll
    for (int dd = 0; dd < 32; ++dd) {
        int d = (dd + h * 4) & 31;
        float w = kwp[d];
        #pragma unroll
        for (int bi = 0; bi < 8; ++bi)
            acc[bi] += qs[(bh * 8 + bi) * 256 + h * 32 + d] * w;
    }
    #pragma unroll
    for (int bi = 0; bi < 8; ++bi) {
        int b = bh * 8 + bi;
        kq[((size_t)(b * 8 + h)) * 256 + c] = acc[bi];
    }

    if (blockIdx.x == 0 && tid < 128) {
        int b = tid >> 3, hh = tid & 7;
        float s = 0.f;
        #pragma unroll
        for (int d = 0; d < 32; ++d) s += qs[b * 256 + hh * 32 + d] * k_b[hh * 32 + d];
        qkb[b * 8 + hh] = s;
    }
}

// ---------------------------------------------------------------------------
// k_gate: a = softmax over {U,T} of (f . fa_w + fa_b); f_cond = a0*U + a1*T;
//         g = sigmoid(f_cond @ gp_w + gp_b).  grid 16 (col chunks), 512 thr.
// Gate scalars computed redundantly per block (trivial work).
// ---------------------------------------------------------------------------
__global__ __launch_bounds__(512) void k_gate(const float* __restrict__ U,
                                              const float* __restrict__ Tt,
                                              const float* __restrict__ fa_w,
                                              const float* __restrict__ fa_b,
                                              const float* __restrict__ gp_w,
                                              const float* __restrict__ gp_b,
                                              float* __restrict__ gout)
{
    __shared__ float xs[8192];          // f_cond [16][512]
    __shared__ float part[32 * 256];
    __shared__ float pd[2][16][32];
    __shared__ float a0s[16], a1s[16];
    int tid = threadIdx.x;

    {
        int b = tid >> 5, sl = tid & 31;
        const float* ub = U  + b * 512 + sl * 16;
        const float* tb = Tt + b * 512 + sl * 16;
        const float* fw = fa_w + sl * 16;
        float su = 0.f, st = 0.f;
        #pragma unroll
        for (int j = 0; j < 16; ++j) { su += ub[j] * fw[j]; st += tb[j] * fw[j]; }
        pd[0][b][sl] = su; pd[1][b][sl] = st;
    }
    __syncthreads();
    if (tid < 16) {
        float s0 = fa_b[0], s1 = fa_b[0];
        #pragma unroll
        for (int sl = 0; sl < 32; ++sl) { s0 += pd[0][tid][sl]; s1 += pd[1][tid][sl]; }
        float mm = fmaxf(s0, s1);
        float e0 = expf(s0 - mm), e1 = expf(s1 - mm);
        float inv = 1.0f / (e0 + e1);
        a0s[tid] = e0 * inv; a1s[tid] = e1 * inv;
    }
    __syncthreads();
    for (int idx = tid; idx < 8192; idx += 512) {
        int b = idx >> 9;
        xs[idx] = a0s[b] * U[idx] + a1s[b] * Tt[idx];
    }
    __syncthreads();

    int cl = tid & 15, ks = tid >> 4;
    int c = blockIdx.x * 16 + cl;
    float acc[16];
    #pragma unroll
    for (int b = 0; b < 16; ++b) acc[b] = 0.f;
    const float* wp = gp_w + (size_t)(ks * 16) * 256 + c;
    #pragma unroll
    for (int i = 0; i < 16; ++i) {
        float w  = wp[(size_t)i * 256];
        int   xi = ks * 16 + i;
        #pragma unroll
        for (int b = 0; b < 16; ++b) acc[b] += xs[b * 512 + xi] * w;
    }
    #pragma unroll
    for (int b = 0; b < 16; ++b) part[ks * 256 + b * 16 + cl] = acc[b];
    __syncthreads();

    if (tid < 256) {
        int b = tid >> 4, cc = tid & 15;
        float s = 0.f;
        #pragma unroll
        for (int k2 = 0; k2 < 32; ++k2) s += part[k2 * 256 + b * 16 + cc];
        s += gp_b[blockIdx.x * 16 + cc];
        gout[b * 256 + blockIdx.x * 16 + cc] = 1.0f / (1.0f + expf(-s));
    }
}

// ---------------------------------------------------------------------------
// K2: score partials.  scores_p[chalf][b][h][t] = sum_{c in half} Fvis[b,c,t]*kq[b,h,c]
// ---------------------------------------------------------------------------
__global__ void k2_scores(const float* __restrict__ F_vis,
                          const float* __restrict__ kq,
                          float* __restrict__ sp)
{
    int chunk = blockIdx.x;          // 0..31
    int b     = blockIdx.y;
    int chalf = chunk >> 4;          // 0..1
    int tch   = chunk & 15;          // 0..15
    int tid   = threadIdx.x;
    int t     = tch*256 + tid;

    __shared__ __align__(16) float kqT[128][8];
    for (int idx = tid; idx < 1024; idx += 256) {
        int h = idx >> 7, cl = idx & 127;
        kqT[cl][h] = kq[(b*NH_ + h)*C_ + chalf*128 + cl];
    }
    __syncthreads();

    const float4* kqT4 = reinterpret_cast<const float4*>(&kqT[0][0]);
    const float* fv = F_vis + ((size_t)b*C_ + chalf*128) * T_ + t;

    float acc[8] = {0,0,0,0,0,0,0,0};
    #pragma unroll 4
    for (int cl = 0; cl < 128; cl++) {
        float v  = fv[(size_t)cl * T_];
        float4 ka = kqT4[cl*2], kb4 = kqT4[cl*2 + 1];
        acc[0] += v*ka.x;  acc[1] += v*ka.y;  acc[2] += v*ka.z;  acc[3] += v*ka.w;
        acc[4] += v*kb4.x; acc[5] += v*kb4.y; acc[6] += v*kb4.z; acc[7] += v*kb4.w;
    }
    #pragma unroll
    for (int h = 0; h < NH_; h++)
        sp[(((size_t)chalf*B_ + b)*NH_ + h)*T_ + t] = acc[h];
}

// ---------------------------------------------------------------------------
// K3: softmax over T per (b,h); writes attn output (output #1)
// ---------------------------------------------------------------------------
__global__ void k3_softmax(const float* __restrict__ sp,
                           const float* __restrict__ qkb,
                           float* __restrict__ attn)
{
    int h = blockIdx.x, b = blockIdx.y, tid = threadIdx.x;
    const float scale = 0.176776695296636893f;  // 32^-0.5
    float bias = qkb[b*NH_ + h];
    const float* p0 = sp + (((size_t)0*B_ + b)*NH_ + h)*T_;
    const float* p1 = sp + (((size_t)1*B_ + b)*NH_ + h)*T_;

    float s[16];
    float m = -1e30f;
    #pragma unroll
    for (int k = 0; k < 16; k++) {
        int t = tid + k*256;
        float v = (p0[t] + p1[t] + bias) * scale;
        s[k] = v; m = fmaxf(m, v);
    }
    __shared__ float red[8];
    #pragma unroll
    for (int o = 32; o; o >>= 1) m = fmaxf(m, __shfl_xor(m, o));
    int wid = tid >> 6, lane = tid & 63;
    if (lane == 0) red[wid] = m;
    __syncthreads();
    m = fmaxf(fmaxf(red[0], red[1]), fmaxf(red[2], red[3]));

    float sum = 0.f;
    #pragma unroll
    for (int k = 0; k < 16; k++) { s[k] = expf(s[k] - m); sum += s[k]; }
    #pragma unroll
    for (int o = 32; o; o >>= 1) sum += __shfl_xor(sum, o);
    if (lane == 0) red[4 + wid] = sum;
    __syncthreads();
    sum = red[4] + red[5] + red[6] + red[7];
    float inv = 1.0f / sum;

    float* ap = attn + ((size_t)b*NH_ + h)*T_;
    #pragma unroll
    for (int k = 0; k < 16; k++) ap[tid + k*256] = s[k] * inv;
}

// ---------------------------------------------------------------------------
// K4: xa[b,h,c] = sum_t attn[b,h,t] * F_vis[b,c,t]   (wave owns 4 channels)
// ---------------------------------------------------------------------------
__global__ void k4_xa(const float* __restrict__ F_vis,
                      const float* __restrict__ attn,
                      float* __restrict__ xa)
{
    int b = blockIdx.y;
    int tid = threadIdx.x, wid = tid >> 6, lane = tid & 63;
    int c0 = blockIdx.x*16 + wid*4;

    const float* ab = attn + (size_t)b*NH_*T_;
    const float* fb = F_vis + (size_t)b*C_*T_;

    float acc[4][8];
    #pragma unroll
    for (int j = 0; j < 4; j++)
        #pragma unroll
        for (int h = 0; h < 8; h++) acc[j][h] = 0.f;

    #pragma unroll 2
    for (int it = 0; it < 64; it++) {
        int t = it*64 + lane;
        float av[8];
        #pragma unroll
        for (int h = 0; h < 8; h++) av[h] = ab[(size_t)h*T_ + t];
        #pragma unroll
        for (int j = 0; j < 4; j++) {
            float v = fb[(size_t)(c0 + j)*T_ + t];
            #pragma unroll
            for (int h = 0; h < 8; h++) acc[j][h] += v * av[h];
        }
    }
    #pragma unroll
    for (int j = 0; j < 4; j++)
        #pragma unroll
        for (int h = 0; h < 8; h++) {
            float v = acc[j][h];
            #pragma unroll
            for (int o = 32; o; o >>= 1) v += __shfl_xor(v, o);
            if (lane == 0) xa[((size_t)b*NH_ + h)*C_ + c0 + j] = v;
        }
}

// ---------------------------------------------------------------------------
// K5: z = (xa @ v_w + v_b) @ o_w + o_b;  gz = g * z
// ---------------------------------------------------------------------------
__global__ void k5_z(const float* __restrict__ xa,
                     const float* __restrict__ v_w, const float* __restrict__ v_b,
                     const float* __restrict__ o_w, const float* __restrict__ o_b,
                     const float* __restrict__ g,   float* __restrict__ gz)
{
    int b = blockIdx.x, j = threadIdx.x;
    __shared__ float zp[C_];
    int h = j >> 5;
    float s = v_b[j];
    const float* xr = xa + ((size_t)b*NH_ + h)*C_;
    #pragma unroll 8
    for (int c = 0; c < C_; c++) s += xr[c] * v_w[c*C_ + j];
    zp[j] = s;
    __syncthreads();
    float z = o_b[j];
    #pragma unroll 8
    for (int i = 0; i < C_; i++) z += zp[i] * o_w[i*C_ + j];
    gz[b*C_ + j] = g[b*C_ + j] * z;
}

// ---------------------------------------------------------------------------
// K6: y = F_vis + gz (broadcast over t); LayerNorm over c; out[b,c,t]
// ---------------------------------------------------------------------------
__global__ void k6_ln(const float* __restrict__ F_vis,
                      const float* __restrict__ gz,
                      const float* __restrict__ ln_g, const float* __restrict__ ln_b,
                      float* __restrict__ out)
{
    int b = blockIdx.y;
    int t = blockIdx.x*256 + threadIdx.x;
    const float* fv  = F_vis + (size_t)b*C_*T_ + t;
    const float* gzb = gz + b*C_;

    float sum = 0.f, sq = 0.f;
    #pragma unroll 8
    for (int c = 0; c < C_; c++) {
        float x = fv[(size_t)c*T_] + gzb[c];
        sum += x; sq += x*x;
    }
    float mu   = sum * (1.0f/C_);
    float var  = sq * (1.0f/C_) - mu*mu;
    float rstd = rsqrtf(fmaxf(var, 0.f) + 1e-5f);

    float* op = out + (size_t)b*C_*T_ + t;
    #pragma unroll 8
    for (int c = 0; c < C_; c++) {
        float x = fv[(size_t)c*T_] + gzb[c];
        op[(size_t)c*T_] = (x - mu)*rstd*ln_g[c] + ln_b[c];
    }
}

// ---------------------------------------------------------------------------
extern "C" void kernel_launch(void* const* d_in, const int* in_sizes, int n_in,
                              void* d_out, int out_size, void* d_ws, size_t ws_size,
                              hipStream_t stream)
{
    const float* F_vis     = (const float*)d_in[0];
    const float* F_text    = (const float*)d_in[1];
    const float* F_unified = (const float*)d_in[2];
    const float* F_teacher = (const float*)d_in[3];
    const float* tp_w1 = (const float*)d_in[4];
    const float* tp_b1 = (const float*)d_in[5];
    const float* tp_w2 = (const float*)d_in[6];
    const float* tp_b2 = (const float*)d_in[7];
    const float* q_w   = (const float*)d_in[8];
    const float* q_b   = (const float*)d_in[9];
    const float* k_w   = (const float*)d_in[10];
    const float* k_b   = (const float*)d_in[11];
    const float* v_w   = (const float*)d_in[12];
    const float* v_b   = (const float*)d_in[13];
    const float* o_w   = (const float*)d_in[14];
    const float* o_b   = (const float*)d_in[15];
    const float* fa_w  = (const float*)d_in[16];
    const float* fa_b  = (const float*)d_in[17];
    const float* gp_w  = (const float*)d_in[18];
    const float* gp_b  = (const float*)d_in[19];
    const float* ln_g  = (const float*)d_in[20];
    const float* ln_b  = (const float*)d_in[21];

    float* ws  = (float*)d_ws;
    float* t1  = ws;                    // 16*256  = 4096
    float* tv  = ws + 4096;             // 4096
    float* qv  = ws + 8192;             // 4096
    float* kq  = ws + 12288;            // 16*8*256 = 32768
    float* qkb = ws + 45056;            // 128
    float* g   = ws + 45184;            // 4096
    float* gz  = ws + 49280;            // 4096
    float* xa  = ws + 53376;            // 32768   (total 86144 floats = 344 KB)

    float* out  = (float*)d_out;
    float* attn = out + (size_t)B_*C_*T_;        // output #1 region
    float* sp   = out;                           // scratch in out-region (overwritten by K6)

    gemm16<512,1><<<16, 512, 0, stream>>>(F_text, tp_w1, tp_b1, t1);
    gemm16<256,0><<<16, 512, 0, stream>>>(t1, tp_w2, tp_b2, tv);
    gemm16<256,0><<<16, 512, 0, stream>>>(tv, q_w, q_b, qv);
    k_kq<<<16, 256, 0, stream>>>(qv, k_w, k_b, kq, qkb);
    k_gate<<<16, 512, 0, stream>>>(F_unified, F_teacher, fa_w, fa_b, gp_w, gp_b, g);

    k2_scores<<<dim3(32, B_), 256, 0, stream>>>(F_vis, kq, sp);
    k3_softmax<<<dim3(NH_, B_), 256, 0, stream>>>(sp, qkb, attn);
    k4_xa<<<dim3(16, B_), 256, 0, stream>>>(F_vis, attn, xa);
    k5_z<<<B_, 256, 0, stream>>>(xa, v_w, v_b, o_w, o_b, g, gz);
    k6_ln<<<dim3(16, B_), 256, 0, stream>>>(F_vis, gz, ln_g, ln_b, out);
}

// Round 4
// 120.049 us; speedup vs baseline: 1.5572x; 1.2172x over previous
//
#include <hip/hip_runtime.h>
#include <math.h>

#define B_  16
#define C_  256
#define T_  4096
#define DT_ 512
#define NH_ 8
#define HD_ 32

// ---------------------------------------------------------------------------
// gemm16<K,ACT>: out[16][256] = act(x[16][K] @ W[K][256] + bias)
// ---------------------------------------------------------------------------
template<int K, int ACT>
__global__ __launch_bounds__(512) void gemm16(const float* __restrict__ x,
                                              const float* __restrict__ W,
                                              const float* __restrict__ bias,
                                              float* __restrict__ out)
{
    __shared__ float xs[16 * K];
    __shared__ float part[32 * 256];
    int tid = threadIdx.x;
    int c0  = blockIdx.x * 16;

    for (int idx = tid; idx < 16 * K; idx += 512) xs[idx] = x[idx];
    __syncthreads();

    int cl = tid & 15;          // col within chunk
    int ks = tid >> 4;          // 0..31 K-slice
    const int Kc = K / 32;
    int c = c0 + cl;

    float acc[16];
    #pragma unroll
    for (int b = 0; b < 16; ++b) acc[b] = 0.f;

    const float* wp = W + (size_t)(ks * Kc) * 256 + c;
    #pragma unroll
    for (int i = 0; i < Kc; ++i) {
        float w  = wp[(size_t)i * 256];
        int   xi = ks * Kc + i;
        #pragma unroll
        for (int b = 0; b < 16; ++b) acc[b] += xs[b * K + xi] * w;
    }
    #pragma unroll
    for (int b = 0; b < 16; ++b) part[ks * 256 + b * 16 + cl] = acc[b];
    __syncthreads();

    if (tid < 256) {
        int b = tid >> 4, cc = tid & 15;
        float s = 0.f;
        #pragma unroll
        for (int k2 = 0; k2 < 32; ++k2) s += part[k2 * 256 + b * 16 + cc];
        s += bias[c0 + cc];
        if (ACT == 1) s = 0.5f * s * (1.0f + erff(s * 0.70710678118654752f));
        out[b * 256 + c0 + cc] = s;
    }
}

// ---------------------------------------------------------------------------
// k_kq: kq[b,h,c] = sum_d k_w[c, h*32+d] * q[b, h*32+d];  qkb[b,h] = q_h . k_b_h
// ---------------------------------------------------------------------------
__global__ __launch_bounds__(256) void k_kq(const float* __restrict__ q,
                                            const float* __restrict__ k_w,
                                            const float* __restrict__ k_b,
                                            float* __restrict__ kq,
                                            float* __restrict__ qkb)
{
    __shared__ float qs[4096];
    int tid = threadIdx.x;
    #pragma unroll
    for (int idx = tid; idx < 4096; idx += 256) qs[idx] = q[idx];
    __syncthreads();

    int cl = tid >> 4;          // 0..15
    int h  = (tid >> 1) & 7;    // 0..7
    int bh = tid & 1;           // 0..1
    int c  = blockIdx.x * 16 + cl;

    const float* kwp = k_w + (size_t)c * 256 + h * 32;
    float acc[8] = {0,0,0,0,0,0,0,0};
    #pragma unroll
    for (int dd = 0; dd < 32; ++dd) {
        int d = (dd + h * 4) & 31;
        float w = kwp[d];
        #pragma unroll
        for (int bi = 0; bi < 8; ++bi)
            acc[bi] += qs[(bh * 8 + bi) * 256 + h * 32 + d] * w;
    }
    #pragma unroll
    for (int bi = 0; bi < 8; ++bi) {
        int b = bh * 8 + bi;
        kq[((size_t)(b * 8 + h)) * 256 + c] = acc[bi];
    }

    if (blockIdx.x == 0 && tid < 128) {
        int b = tid >> 3, hh = tid & 7;
        float s = 0.f;
        #pragma unroll
        for (int d = 0; d < 32; ++d) s += qs[b * 256 + hh * 32 + d] * k_b[hh * 32 + d];
        qkb[b * 8 + hh] = s;
    }
}

// ---------------------------------------------------------------------------
// k_gate
// ---------------------------------------------------------------------------
__global__ __launch_bounds__(512) void k_gate(const float* __restrict__ U,
                                              const float* __restrict__ Tt,
                                              const float* __restrict__ fa_w,
                                              const float* __restrict__ fa_b,
                                              const float* __restrict__ gp_w,
                                              const float* __restrict__ gp_b,
                                              float* __restrict__ gout)
{
    __shared__ float xs[8192];          // f_cond [16][512]
    __shared__ float part[32 * 256];
    __shared__ float pd[2][16][32];
    __shared__ float a0s[16], a1s[16];
    int tid = threadIdx.x;

    {
        int b = tid >> 5, sl = tid & 31;
        const float* ub = U  + b * 512 + sl * 16;
        const float* tb = Tt + b * 512 + sl * 16;
        const float* fw = fa_w + sl * 16;
        float su = 0.f, st = 0.f;
        #pragma unroll
        for (int j = 0; j < 16; ++j) { su += ub[j] * fw[j]; st += tb[j] * fw[j]; }
        pd[0][b][sl] = su; pd[1][b][sl] = st;
    }
    __syncthreads();
    if (tid < 16) {
        float s0 = fa_b[0], s1 = fa_b[0];
        #pragma unroll
        for (int sl = 0; sl < 32; ++sl) { s0 += pd[0][tid][sl]; s1 += pd[1][tid][sl]; }
        float mm = fmaxf(s0, s1);
        float e0 = expf(s0 - mm), e1 = expf(s1 - mm);
        float inv = 1.0f / (e0 + e1);
        a0s[tid] = e0 * inv; a1s[tid] = e1 * inv;
    }
    __syncthreads();
    for (int idx = tid; idx < 8192; idx += 512) {
        int b = idx >> 9;
        xs[idx] = a0s[b] * U[idx] + a1s[b] * Tt[idx];
    }
    __syncthreads();

    int cl = tid & 15, ks = tid >> 4;
    int c = blockIdx.x * 16 + cl;
    float acc[16];
    #pragma unroll
    for (int b = 0; b < 16; ++b) acc[b] = 0.f;
    const float* wp = gp_w + (size_t)(ks * 16) * 256 + c;
    #pragma unroll
    for (int i = 0; i < 16; ++i) {
        float w  = wp[(size_t)i * 256];
        int   xi = ks * 16 + i;
        #pragma unroll
        for (int b = 0; b < 16; ++b) acc[b] += xs[b * 512 + xi] * w;
    }
    #pragma unroll
    for (int b = 0; b < 16; ++b) part[ks * 256 + b * 16 + cl] = acc[b];
    __syncthreads();

    if (tid < 256) {
        int b = tid >> 4, cc = tid & 15;
        float s = 0.f;
        #pragma unroll
        for (int k2 = 0; k2 < 32; ++k2) s += part[k2 * 256 + b * 16 + cc];
        s += gp_b[blockIdx.x * 16 + cc];
        gout[b * 256 + blockIdx.x * 16 + cc] = 1.0f / (1.0f + expf(-s));
    }
}

// ---------------------------------------------------------------------------
// K2: score partials, float4 along t, c split 4-way.
// sp[cq][b][h][t] = sum_{c in quarter} Fvis[b,c,t]*kq[b,h,c]
// grid: (16, B): bx>>2 = cq, bx&3 = tc.  256 thr, thread owns 4 t.
// ---------------------------------------------------------------------------
__global__ __launch_bounds__(256) void k2_scores(const float* __restrict__ F_vis,
                                                 const float* __restrict__ kq,
                                                 float* __restrict__ sp)
{
    int bx = blockIdx.x;
    int b  = blockIdx.y;
    int cq = bx >> 2;
    int tc = bx & 3;
    int tid = threadIdx.x;
    int t  = tc * 1024 + tid * 4;

    __shared__ float kqs[64][8];
    for (int idx = tid; idx < 512; idx += 256) {
        int h = idx & 7, cl = idx >> 3;
        kqs[cl][h] = kq[((size_t)(b * NH_ + h)) * C_ + cq * 64 + cl];
    }
    __syncthreads();

    const float* fv = F_vis + ((size_t)b * C_ + cq * 64) * T_ + t;

    float4 acc[8];
    #pragma unroll
    for (int h = 0; h < 8; ++h) acc[h] = make_float4(0.f, 0.f, 0.f, 0.f);

    for (int cl = 0; cl < 64; ++cl) {
        float4 v = *reinterpret_cast<const float4*>(&fv[(size_t)cl * T_]);
        #pragma unroll
        for (int h = 0; h < 8; ++h) {
            float w = kqs[cl][h];
            acc[h].x += v.x * w; acc[h].y += v.y * w;
            acc[h].z += v.z * w; acc[h].w += v.w * w;
        }
    }
    #pragma unroll
    for (int h = 0; h < 8; ++h)
        *reinterpret_cast<float4*>(&sp[(((size_t)cq * B_ + b) * NH_ + h) * T_ + t]) = acc[h];
}

// ---------------------------------------------------------------------------
// K3: softmax over T per (b,h) from 4 partials; writes attn output
// ---------------------------------------------------------------------------
__global__ __launch_bounds__(256) void k3_softmax(const float* __restrict__ sp,
                                                  const float* __restrict__ qkb,
                                                  float* __restrict__ attn)
{
    int h = blockIdx.x, b = blockIdx.y, tid = threadIdx.x;
    const float scale = 0.176776695296636893f;  // 32^-0.5
    float bias = qkb[b * NH_ + h];
    const float* p0 = sp + (((size_t)0 * B_ + b) * NH_ + h) * T_;
    const float* p1 = sp + (((size_t)1 * B_ + b) * NH_ + h) * T_;
    const float* p2 = sp + (((size_t)2 * B_ + b) * NH_ + h) * T_;
    const float* p3 = sp + (((size_t)3 * B_ + b) * NH_ + h) * T_;

    float4 sv[4];
    float m = -1e30f;
    #pragma unroll
    for (int k = 0; k < 4; ++k) {
        int t = k * 1024 + tid * 4;
        float4 a = *reinterpret_cast<const float4*>(&p0[t]);
        float4 c = *reinterpret_cast<const float4*>(&p1[t]);
        float4 d = *reinterpret_cast<const float4*>(&p2[t]);
        float4 e = *reinterpret_cast<const float4*>(&p3[t]);
        float4 v;
        v.x = (a.x + c.x + d.x + e.x + bias) * scale;
        v.y = (a.y + c.y + d.y + e.y + bias) * scale;
        v.z = (a.z + c.z + d.z + e.z + bias) * scale;
        v.w = (a.w + c.w + d.w + e.w + bias) * scale;
        sv[k] = v;
        m = fmaxf(m, fmaxf(fmaxf(v.x, v.y), fmaxf(v.z, v.w)));
    }
    __shared__ float red[8];
    #pragma unroll
    for (int o = 32; o; o >>= 1) m = fmaxf(m, __shfl_xor(m, o));
    int wid = tid >> 6, lane = tid & 63;
    if (lane == 0) red[wid] = m;
    __syncthreads();
    m = fmaxf(fmaxf(red[0], red[1]), fmaxf(red[2], red[3]));

    float sum = 0.f;
    #pragma unroll
    for (int k = 0; k < 4; ++k) {
        sv[k].x = expf(sv[k].x - m); sv[k].y = expf(sv[k].y - m);
        sv[k].z = expf(sv[k].z - m); sv[k].w = expf(sv[k].w - m);
        sum += sv[k].x + sv[k].y + sv[k].z + sv[k].w;
    }
    #pragma unroll
    for (int o = 32; o; o >>= 1) sum += __shfl_xor(sum, o);
    if (lane == 0) red[4 + wid] = sum;
    __syncthreads();
    sum = red[4] + red[5] + red[6] + red[7];
    float inv = 1.0f / sum;

    float* ap = attn + ((size_t)b * NH_ + h) * T_;
    #pragma unroll
    for (int k = 0; k < 4; ++k) {
        float4 v = sv[k];
        v.x *= inv; v.y *= inv; v.z *= inv; v.w *= inv;
        *reinterpret_cast<float4*>(&ap[k * 1024 + tid * 4]) = v;
    }
}

// ---------------------------------------------------------------------------
// K4: xa[b,h,c] = sum_t attn[b,h,t] * F_vis[b,c,t], float4 along t.
// wave owns 4 channels; 16 iterations of 256 t.
// ---------------------------------------------------------------------------
__global__ __launch_bounds__(256, 2) void k4_xa(const float* __restrict__ F_vis,
                                                const float* __restrict__ attn,
                                                float* __restrict__ xa)
{
    int b = blockIdx.y;
    int tid = threadIdx.x, wid = tid >> 6, lane = tid & 63;
    int c0 = blockIdx.x * 16 + wid * 4;

    const float* ab = attn + (size_t)b * NH_ * T_;
    const float* fb = F_vis + (size_t)b * C_ * T_;

    float4 acc[4][8];
    #pragma unroll
    for (int j = 0; j < 4; ++j)
        #pragma unroll
        for (int h = 0; h < 8; ++h) acc[j][h] = make_float4(0.f, 0.f, 0.f, 0.f);

    for (int it = 0; it < 16; ++it) {
        int t = it * 256 + lane * 4;
        float4 av[8];
        #pragma unroll
        for (int h = 0; h < 8; ++h)
            av[h] = *reinterpret_cast<const float4*>(&ab[(size_t)h * T_ + t]);
        #pragma unroll
        for (int j = 0; j < 4; ++j) {
            float4 f = *reinterpret_cast<const float4*>(&fb[(size_t)(c0 + j) * T_ + t]);
            #pragma unroll
            for (int h = 0; h < 8; ++h) {
                acc[j][h].x += f.x * av[h].x; acc[j][h].y += f.y * av[h].y;
                acc[j][h].z += f.z * av[h].z; acc[j][h].w += f.w * av[h].w;
            }
        }
    }
    #pragma unroll
    for (int j = 0; j < 4; ++j)
        #pragma unroll
        for (int h = 0; h < 8; ++h) {
            float v = acc[j][h].x + acc[j][h].y + acc[j][h].z + acc[j][h].w;
            #pragma unroll
            for (int o = 32; o; o >>= 1) v += __shfl_xor(v, o);
            if (lane == 0) xa[((size_t)b * NH_ + h) * C_ + c0 + j] = v;
        }
}

// ---------------------------------------------------------------------------
// K5: z = (xa @ v_w + v_b) @ o_w + o_b;  gz = g * z
// ---------------------------------------------------------------------------
__global__ void k5_z(const float* __restrict__ xa,
                     const float* __restrict__ v_w, const float* __restrict__ v_b,
                     const float* __restrict__ o_w, const float* __restrict__ o_b,
                     const float* __restrict__ g,   float* __restrict__ gz)
{
    int b = blockIdx.x, j = threadIdx.x;
    __shared__ float zp[C_];
    int h = j >> 5;
    float s = v_b[j];
    const float* xr = xa + ((size_t)b * NH_ + h) * C_;
    #pragma unroll 8
    for (int c = 0; c < C_; c++) s += xr[c] * v_w[c * C_ + j];
    zp[j] = s;
    __syncthreads();
    float z = o_b[j];
    #pragma unroll 8
    for (int i = 0; i < C_; i++) z += zp[i] * o_w[i * C_ + j];
    gz[b * C_ + j] = g[b * C_ + j] * z;
}

// ---------------------------------------------------------------------------
// K6: LDS-tiled fused residual+gate+LayerNorm.
// Block handles [256 c][32 t]; float4 loads/stores; one global read per elem.
// tile row stride 36 floats (16B-aligned, shifts banks by 4/row).
// ---------------------------------------------------------------------------
__global__ __launch_bounds__(256) void k6_ln(const float* __restrict__ F_vis,
                                             const float* __restrict__ gz,
                                             const float* __restrict__ ln_g,
                                             const float* __restrict__ ln_b,
                                             float* __restrict__ out)
{
    int b  = blockIdx.y;
    int t0 = blockIdx.x * 32;
    int tid = threadIdx.x;

    __shared__ __align__(16) float tile[256][36];
    __shared__ float lgs[256], lbs[256], gzs[256];
    __shared__ float redS[8][32], redQ[8][32];
    __shared__ float mus[32], rss[32];

    lgs[tid] = ln_g[tid];
    lbs[tid] = ln_b[tid];
    gzs[tid] = gz[b * C_ + tid];
    __syncthreads();

    const float* fvb = F_vis + (size_t)b * C_ * T_ + t0;
    #pragma unroll
    for (int k = 0; k < 8; ++k) {
        int s = tid + k * 256;
        int c = s >> 3, t4 = s & 7;
        float4 v = *reinterpret_cast<const float4*>(&fvb[(size_t)c * T_ + t4 * 4]);
        float gc = gzs[c];
        v.x += gc; v.y += gc; v.z += gc; v.w += gc;
        *reinterpret_cast<float4*>(&tile[c][t4 * 4]) = v;
    }
    __syncthreads();

    // per-t sum/sumsq: 8 threads per t, 32 c each
    {
        int t = tid & 31, cs = tid >> 5;
        float s = 0.f, q = 0.f;
        #pragma unroll
        for (int j = 0; j < 32; ++j) {
            float v = tile[cs * 32 + j][t];
            s += v; q += v * v;
        }
        redS[cs][t] = s; redQ[cs][t] = q;
    }
    __syncthreads();
    if (tid < 32) {
        float s = 0.f, q = 0.f;
        #pragma unroll
        for (int cs = 0; cs < 8; ++cs) { s += redS[cs][tid]; q += redQ[cs][tid]; }
        float mu  = s * (1.0f / C_);
        float var = q * (1.0f / C_) - mu * mu;
        mus[tid] = mu;
        rss[tid] = rsqrtf(fmaxf(var, 0.f) + 1e-5f);
    }
    __syncthreads();

    float* ob = out + (size_t)b * C_ * T_ + t0;
    #pragma unroll
    for (int k = 0; k < 8; ++k) {
        int s = tid + k * 256;
        int c = s >> 3, t4 = s & 7;
        float4 v = *reinterpret_cast<const float4*>(&tile[c][t4 * 4]);
        float lg = lgs[c], lb = lbs[c];
        float4 o;
        o.x = (v.x - mus[t4 * 4 + 0]) * rss[t4 * 4 + 0] * lg + lb;
        o.y = (v.y - mus[t4 * 4 + 1]) * rss[t4 * 4 + 1] * lg + lb;
        o.z = (v.z - mus[t4 * 4 + 2]) * rss[t4 * 4 + 2] * lg + lb;
        o.w = (v.w - mus[t4 * 4 + 3]) * rss[t4 * 4 + 3] * lg + lb;
        *reinterpret_cast<float4*>(&ob[(size_t)c * T_ + t4 * 4]) = o;
    }
}

// ---------------------------------------------------------------------------
extern "C" void kernel_launch(void* const* d_in, const int* in_sizes, int n_in,
                              void* d_out, int out_size, void* d_ws, size_t ws_size,
                              hipStream_t stream)
{
    const float* F_vis     = (const float*)d_in[0];
    const float* F_text    = (const float*)d_in[1];
    const float* F_unified = (const float*)d_in[2];
    const float* F_teacher = (const float*)d_in[3];
    const float* tp_w1 = (const float*)d_in[4];
    const float* tp_b1 = (const float*)d_in[5];
    const float* tp_w2 = (const float*)d_in[6];
    const float* tp_b2 = (const float*)d_in[7];
    const float* q_w   = (const float*)d_in[8];
    const float* q_b   = (const float*)d_in[9];
    const float* k_w   = (const float*)d_in[10];
    const float* k_b   = (const float*)d_in[11];
    const float* v_w   = (const float*)d_in[12];
    const float* v_b   = (const float*)d_in[13];
    const float* o_w   = (const float*)d_in[14];
    const float* o_b   = (const float*)d_in[15];
    const float* fa_w  = (const float*)d_in[16];
    const float* fa_b  = (const float*)d_in[17];
    const float* gp_w  = (const float*)d_in[18];
    const float* gp_b  = (const float*)d_in[19];
    const float* ln_g  = (const float*)d_in[20];
    const float* ln_b  = (const float*)d_in[21];

    float* ws  = (float*)d_ws;
    float* t1  = ws;                    // 4096
    float* tv  = ws + 4096;             // 4096
    float* qv  = ws + 8192;             // 4096
    float* kq  = ws + 12288;            // 32768
    float* qkb = ws + 45056;            // 128
    float* g   = ws + 45184;            // 4096
    float* gz  = ws + 49280;            // 4096
    float* xa  = ws + 53376;            // 32768

    float* out  = (float*)d_out;
    float* attn = out + (size_t)B_ * C_ * T_;    // output #1 region
    float* sp   = out;                           // scratch in y-region (4 partials, 8 MiB)

    gemm16<512, 1><<<16, 512, 0, stream>>>(F_text, tp_w1, tp_b1, t1);
    gemm16<256, 0><<<16, 512, 0, stream>>>(t1, tp_w2, tp_b2, tv);
    gemm16<256, 0><<<16, 512, 0, stream>>>(tv, q_w, q_b, qv);
    k_kq<<<16, 256, 0, stream>>>(qv, k_w, k_b, kq, qkb);
    k_gate<<<16, 512, 0, stream>>>(F_unified, F_teacher, fa_w, fa_b, gp_w, gp_b, g);

    k2_scores<<<dim3(16, B_), 256, 0, stream>>>(F_vis, kq, sp);
    k3_softmax<<<dim3(NH_, B_), 256, 0, stream>>>(sp, qkb, attn);
    k4_xa<<<dim3(16, B_), 256, 0, stream>>>(F_vis, attn, xa);
    k5_z<<<B_, 256, 0, stream>>>(xa, v_w, v_b, o_w, o_b, g, gz);
    k6_ln<<<dim3(128, B_), 256, 0, stream>>>(F_vis, gz, ln_g, ln_b, out);
}